// Round 1
// baseline (672.167 us; speedup 1.0000x reference)
//
#include <hip/hip_runtime.h>

// out = 1 - (1/B) * sum_c || sum_{b: label_b=c} x_b/||x_b|| ||
// (algebraically identical to the reference: counts and the prototype
//  normalization cancel inside the summed dot products)

#define DIM 256        // feature dim (fixed by problem setup)
#define G 8            // classes per accumulation block
#define MAXCHUNK 16    // max B-chunks (ws partial copies of the C*D sum table)

// ---------------------------------------------------------------------------
// Pass 1: per-(class-group, B-chunk) block scans its label chunk; on a match
// the whole wave gathers the feature row, L2-normalizes it (wave reduce), and
// accumulates into an LDS tile. Deterministic: partial sums per chunk go to
// disjoint ws regions (no global atomics).
// ---------------------------------------------------------------------------
__global__ __launch_bounds__(256) void proto_accum(
    const float* __restrict__ x, const int* __restrict__ labels,
    float* __restrict__ partials, int B, int C, int nchunk) {
  __shared__ float s_sums[G * DIM];  // 8 KB
  const int tid  = threadIdx.x;
  const int lane = tid & 63;
  const int g0   = blockIdx.x * G;   // first class of this block's group
  const int chunk = blockIdx.y;

  for (int i = tid; i < G * DIM; i += 256) s_sums[i] = 0.f;
  __syncthreads();

  const int Bc = (B + nchunk - 1) / nchunk;
  const int r0 = chunk * Bc;
  const int r1 = min(B, r0 + Bc);

  for (int i0 = r0; i0 < r1; i0 += 256) {
    const int i = i0 + tid;
    int rel = -1;
    if (i < r1) {
      const unsigned r = (unsigned)(labels[i] - g0);
      if (r < (unsigned)G) rel = (int)r;
    }
    unsigned long long mask = __ballot(rel >= 0);
    while (mask) {
      const int src = __ffsll(mask) - 1;
      mask &= mask - 1;
      const int rrow = __shfl(i, src);     // matched row index
      const int rrel = __shfl(rel, src);   // class slot within group
      const float* xp = x + (size_t)rrow * DIM;
      // stride-64 per lane: coalesced 256B global loads, conflict-free LDS
      const float v0 = xp[lane];
      const float v1 = xp[lane + 64];
      const float v2 = xp[lane + 128];
      const float v3 = xp[lane + 192];
      float ss = v0 * v0 + v1 * v1 + v2 * v2 + v3 * v3;
#pragma unroll
      for (int off = 32; off; off >>= 1) ss += __shfl_xor(ss, off);
      const float inv = 1.f / fmaxf(sqrtf(ss), 1e-12f);  // matches F.normalize eps
      atomicAdd(&s_sums[rrel * DIM + lane],       v0 * inv);
      atomicAdd(&s_sums[rrel * DIM + lane + 64],  v1 * inv);
      atomicAdd(&s_sums[rrel * DIM + lane + 128], v2 * inv);
      atomicAdd(&s_sums[rrel * DIM + lane + 192], v3 * inv);
    }
  }
  __syncthreads();

  // flush LDS tile to this chunk's partial table (disjoint, non-atomic)
  float* dst = partials + ((size_t)chunk * C + g0) * DIM;
  for (int i = tid; i < G * DIM; i += 256) {
    if (g0 + i / DIM < C) dst[i] = s_sums[i];
  }
}

// ---------------------------------------------------------------------------
// Pass 2: one wave per class: reduce partials over chunks, take ||S_c||,
// block-sum, one atomicAdd per block into out[0].
// ---------------------------------------------------------------------------
__global__ __launch_bounds__(256) void proto_norm(
    const float* __restrict__ partials, float* __restrict__ out,
    int C, int nchunk) {
  const int wave = threadIdx.x >> 6;
  const int lane = threadIdx.x & 63;
  const int c = blockIdx.x * 4 + wave;
  float term = 0.f;
  if (c < C) {
    float4 acc = make_float4(0.f, 0.f, 0.f, 0.f);
    for (int k = 0; k < nchunk; ++k) {
      const float4* p =
          (const float4*)(partials + ((size_t)k * C + c) * DIM);
      const float4 v = p[lane];  // 16B/lane, coalesced 1KB/wave
      acc.x += v.x; acc.y += v.y; acc.z += v.z; acc.w += v.w;
    }
    float ss = acc.x * acc.x + acc.y * acc.y + acc.z * acc.z + acc.w * acc.w;
#pragma unroll
    for (int off = 32; off; off >>= 1) ss += __shfl_xor(ss, off);
    term = sqrtf(ss);  // == ||S_c|| ; 0 for empty classes, matching reference
  }
  __shared__ float s_part[4];
  if (lane == 0) s_part[wave] = term;
  __syncthreads();
  if (threadIdx.x == 0)
    atomicAdd(out, s_part[0] + s_part[1] + s_part[2] + s_part[3]);
}

__global__ void proto_final(float* __restrict__ out, int B) {
  out[0] = 1.f - out[0] / (float)B;
}

extern "C" void kernel_launch(void* const* d_in, const int* in_sizes, int n_in,
                              void* d_out, int out_size, void* d_ws, size_t ws_size,
                              hipStream_t stream) {
  const float* x      = (const float*)d_in[0];
  const int*   labels = (const int*)d_in[1];
  const int B = in_sizes[1];
  const int C = 1000;  // fixed by problem setup (num_classes lives device-side)

  // pick as many B-chunks as the workspace allows (each needs C*DIM floats)
  int nchunk = MAXCHUNK;
  while (nchunk > 1 &&
         (size_t)nchunk * C * DIM * sizeof(float) > ws_size)
    nchunk >>= 1;

  float* partials = (float*)d_ws;

  hipMemsetAsync(d_out, 0, sizeof(float), stream);

  dim3 grid1((C + G - 1) / G, nchunk);
  proto_accum<<<grid1, 256, 0, stream>>>(x, labels, partials, B, C, nchunk);
  proto_norm<<<(C + 3) / 4, 256, 0, stream>>>(partials, (float*)d_out, C, nchunk);
  proto_final<<<1, 1, 0, stream>>>((float*)d_out, B);
}

// Round 2
// 500.358 us; speedup vs baseline: 1.3434x; 1.3434x over previous
//
#include <hip/hip_runtime.h>

// out = 1 - (1/B) * sum_c || sum_{b: label_b=c} x_b/||x_b|| ||
// Pipeline: histogram -> prefix scan -> counting-sort permutation ->
// streaming segmented sum over class-sorted rows -> per-class norms.

#define DIM 256    // feature dim (fixed by problem setup)
#define NB 64      // histogram / permutation blocks
#define PBLK 512   // segmented-sum blocks

// ---------------------------------------------------------------------------
// K1: per-block label histogram (LDS-privatized, no global atomics)
// ---------------------------------------------------------------------------
__global__ __launch_bounds__(256) void k_hist(const int* __restrict__ labels,
                                              int* __restrict__ hist,
                                              int B, int C) {
  extern __shared__ int s_h[];  // C ints
  const int tid = threadIdx.x;
  for (int c = tid; c < C; c += 256) s_h[c] = 0;
  __syncthreads();
  const int chunk = (B + NB - 1) / NB;
  const int r0 = blockIdx.x * chunk;
  const int r1 = min(B, r0 + chunk);
  for (int i = r0 + tid; i < r1; i += 256) atomicAdd(&s_h[labels[i]], 1);
  __syncthreads();
  int* dst = hist + (size_t)blockIdx.x * C;
  for (int c = tid; c < C; c += 256) dst[c] = s_h[c];
}

// ---------------------------------------------------------------------------
// K2: single block. hist[b][c] -> bases[b][c] = class_offset[c] + prefix_b(hist)
// ---------------------------------------------------------------------------
__global__ __launch_bounds__(1024) void k_scan(int* __restrict__ hist, int C) {
  __shared__ int s[2][1024];
  const int tid = threadIdx.x;
  int total = 0;
  if (tid < C) {
    int run = 0;
    for (int b = 0; b < NB; ++b) {
      int* p = hist + (size_t)b * C + tid;  // coalesced across tid
      const int h = *p;
      *p = run;  // within-class prefix over blocks
      run += h;
    }
    total = run;
  }
  int cur = 0;
  s[0][tid] = total;
  __syncthreads();
  for (int d = 1; d < 1024; d <<= 1) {  // Hillis-Steele inclusive scan
    const int v = s[cur][tid] + (tid >= d ? s[cur][tid - d] : 0);
    s[1 - cur][tid] = v;
    __syncthreads();
    cur ^= 1;
  }
  const int exoff = s[cur][tid] - total;  // exclusive class offset
  if (tid < C)
    for (int b = 0; b < NB; ++b) hist[(size_t)b * C + tid] += exoff;
}

// ---------------------------------------------------------------------------
// K3: counting-sort scatter: pr[pos] = (row, label), pos from LDS cursors
// ---------------------------------------------------------------------------
__global__ __launch_bounds__(256) void k_permute(const int* __restrict__ labels,
                                                 const int* __restrict__ bases,
                                                 int2* __restrict__ pr,
                                                 int B, int C) {
  extern __shared__ int s_cur[];  // C ints
  const int tid = threadIdx.x;
  const int* bp = bases + (size_t)blockIdx.x * C;
  for (int c = tid; c < C; c += 256) s_cur[c] = bp[c];
  __syncthreads();
  const int chunk = (B + NB - 1) / NB;
  const int r0 = blockIdx.x * chunk;
  const int r1 = min(B, r0 + chunk);
  for (int i = r0 + tid; i < r1; i += 256) {
    const int l = labels[i];
    const int pos = atomicAdd(&s_cur[l], 1);
    pr[pos] = make_int2(i, l);
  }
}

// ---------------------------------------------------------------------------
// K4: streaming segmented sum over class-sorted rows. One wave per contiguous
// run; float4/lane register accumulator; flush only at class boundaries.
// Next row is software-prefetched so the 1 KB row load overlaps the reduce.
// ---------------------------------------------------------------------------
__global__ __launch_bounds__(256) void k_segsum(const float* __restrict__ x,
                                                const int2* __restrict__ pr,
                                                float* __restrict__ sums,
                                                int B) {
  const int lane = threadIdx.x & 63;
  const int wave = threadIdx.x >> 6;
  const int wid = blockIdx.x * 4 + wave;
  const int nw = PBLK * 4;
  const int per = (B + nw - 1) / nw;
  const int r0 = wid * per;
  const int r1 = min(B, r0 + per);
  if (r0 >= r1) return;

  float4 acc = make_float4(0.f, 0.f, 0.f, 0.f);
  int prev = -1;

  int2 cur = pr[r0];
  float4 v = ((const float4*)(x + (size_t)cur.x * DIM))[lane];

  for (int r = r0; r < r1; ++r) {
    int2 nxt = make_int2(0, 0);
    float4 nv = make_float4(0.f, 0.f, 0.f, 0.f);
    if (r + 1 < r1) {
      nxt = pr[r + 1];  // wave-uniform broadcast load
      nv = ((const float4*)(x + (size_t)nxt.x * DIM))[lane];  // prefetch 1 KB
    }
    // normalize current row: wave-reduce sum of squares
    float ss = v.x * v.x + v.y * v.y + v.z * v.z + v.w * v.w;
#pragma unroll
    for (int off = 32; off; off >>= 1) ss += __shfl_xor(ss, off);
    const float inv = 1.f / fmaxf(sqrtf(ss), 1e-12f);  // matches F.normalize eps
    if (cur.y != prev) {  // wave-uniform branch
      if (prev >= 0) {
        float* dst = sums + (size_t)prev * DIM + lane * 4;
        atomicAdd(dst + 0, acc.x);
        atomicAdd(dst + 1, acc.y);
        atomicAdd(dst + 2, acc.z);
        atomicAdd(dst + 3, acc.w);
      }
      acc = make_float4(0.f, 0.f, 0.f, 0.f);
      prev = cur.y;
    }
    acc.x += v.x * inv; acc.y += v.y * inv;
    acc.z += v.z * inv; acc.w += v.w * inv;
    cur = nxt; v = nv;
  }
  if (prev >= 0) {
    float* dst = sums + (size_t)prev * DIM + lane * 4;
    atomicAdd(dst + 0, acc.x);
    atomicAdd(dst + 1, acc.y);
    atomicAdd(dst + 2, acc.z);
    atomicAdd(dst + 3, acc.w);
  }
}

// ---------------------------------------------------------------------------
// K5: per-class norm, block-sum, one atomic per block into out[0]; then final.
// ---------------------------------------------------------------------------
__global__ __launch_bounds__(256) void k_norm(const float* __restrict__ sums,
                                              float* __restrict__ out, int C) {
  const int wave = threadIdx.x >> 6;
  const int lane = threadIdx.x & 63;
  const int c = blockIdx.x * 4 + wave;
  float term = 0.f;
  if (c < C) {
    const float4 v = ((const float4*)(sums + (size_t)c * DIM))[lane];
    float ss = v.x * v.x + v.y * v.y + v.z * v.z + v.w * v.w;
#pragma unroll
    for (int off = 32; off; off >>= 1) ss += __shfl_xor(ss, off);
    term = sqrtf(ss);  // 0 for empty classes, matching reference
  }
  __shared__ float sp[4];
  if (lane == 0) sp[wave] = term;
  __syncthreads();
  if (threadIdx.x == 0) atomicAdd(out, sp[0] + sp[1] + sp[2] + sp[3]);
}

__global__ void k_final(float* __restrict__ out, int B) {
  out[0] = 1.f - out[0] / (float)B;
}

extern "C" void kernel_launch(void* const* d_in, const int* in_sizes, int n_in,
                              void* d_out, int out_size, void* d_ws, size_t ws_size,
                              hipStream_t stream) {
  const float* x      = (const float*)d_in[0];
  const int*   labels = (const int*)d_in[1];
  const int B = in_sizes[1];
  const int C = 1000;  // fixed by problem setup

  // ws layout: hist[NB*C] ints | pr[B] int2 | sums[C*DIM] floats
  char* ws = (char*)d_ws;
  int*   hist = (int*)ws;
  size_t off = ((size_t)NB * C * sizeof(int) + 15) & ~(size_t)15;
  int2*  pr   = (int2*)(ws + off);
  off += (size_t)B * sizeof(int2);
  float* sums = (float*)(ws + off);

  hipMemsetAsync(d_out, 0, sizeof(float), stream);
  hipMemsetAsync(sums, 0, (size_t)C * DIM * sizeof(float), stream);

  const size_t lds_c = (size_t)C * sizeof(int);
  k_hist<<<NB, 256, lds_c, stream>>>(labels, hist, B, C);
  k_scan<<<1, 1024, 0, stream>>>(hist, C);
  k_permute<<<NB, 256, lds_c, stream>>>(labels, hist, pr, B, C);
  k_segsum<<<PBLK, 256, 0, stream>>>(x, pr, sums, B);
  k_norm<<<(C + 3) / 4, 256, 0, stream>>>(sums, (float*)d_out, C);
  k_final<<<1, 1, 0, stream>>>((float*)d_out, B);
}

// Round 4
// 394.318 us; speedup vs baseline: 1.7046x; 1.2689x over previous
//
#include <hip/hip_runtime.h>

// out = 1 - (1/B) * sum_c || sum_{b: label_b=c} x_b/||x_b|| ||
// Pipeline: histogram -> prefix scan -> counting-sort permutation ->
// streaming segmented sum over class-sorted rows -> per-class norms.

#define DIM 256       // feature dim (fixed by problem setup)
#define NB 64         // histogram / permutation blocks
#define SSB 2048      // segmented-sum blocks: 8192 waves = full occupancy

typedef float fx4 __attribute__((ext_vector_type(4)));  // nontemporal-friendly

// ---------------------------------------------------------------------------
// K1: per-block label histogram (LDS-privatized); also zeroes the sums table
// so no separate memset dispatch is needed.
// ---------------------------------------------------------------------------
__global__ __launch_bounds__(256) void k_hist(const int* __restrict__ labels,
                                              int* __restrict__ hist,
                                              float* __restrict__ sums,
                                              int B, int C) {
  extern __shared__ int s_h[];  // C ints
  const int tid = threadIdx.x;
  for (int i = blockIdx.x * 256 + tid; i < C * DIM; i += NB * 256)
    sums[i] = 0.f;
  for (int c = tid; c < C; c += 256) s_h[c] = 0;
  __syncthreads();
  const int chunk = (B + NB - 1) / NB;
  const int r0 = blockIdx.x * chunk;
  const int r1 = min(B, r0 + chunk);
  for (int i = r0 + tid; i < r1; i += 256) atomicAdd(&s_h[labels[i]], 1);
  __syncthreads();
  int* dst = hist + (size_t)blockIdx.x * C;
  for (int c = tid; c < C; c += 256) dst[c] = s_h[c];
}

// ---------------------------------------------------------------------------
// K2: single block. hist[b][c] -> bases[b][c] = class_offset[c] + prefix_b.
// Also zeroes out[0] (runs before k_norm's atomics).
// ---------------------------------------------------------------------------
__global__ __launch_bounds__(1024) void k_scan(int* __restrict__ hist,
                                               float* __restrict__ out, int C) {
  __shared__ int s[2][1024];
  const int tid = threadIdx.x;
  if (tid == 0) out[0] = 0.f;
  int total = 0;
  if (tid < C) {
    int run = 0;
    for (int b = 0; b < NB; ++b) {
      int* p = hist + (size_t)b * C + tid;  // coalesced across tid
      const int h = *p;
      *p = run;  // within-class prefix over blocks
      run += h;
    }
    total = run;
  }
  int cur = 0;
  s[0][tid] = total;
  __syncthreads();
  for (int d = 1; d < 1024; d <<= 1) {  // Hillis-Steele inclusive scan
    const int v = s[cur][tid] + (tid >= d ? s[cur][tid - d] : 0);
    s[1 - cur][tid] = v;
    __syncthreads();
    cur ^= 1;
  }
  const int exoff = s[cur][tid] - total;  // exclusive class offset
  if (tid < C)
    for (int b = 0; b < NB; ++b) hist[(size_t)b * C + tid] += exoff;
}

// ---------------------------------------------------------------------------
// K3: counting-sort scatter: pr[pos] = (row, label), pos from LDS cursors
// ---------------------------------------------------------------------------
__global__ __launch_bounds__(256) void k_permute(const int* __restrict__ labels,
                                                 const int* __restrict__ bases,
                                                 int2* __restrict__ pr,
                                                 int B, int C) {
  extern __shared__ int s_cur[];  // C ints
  const int tid = threadIdx.x;
  const int* bp = bases + (size_t)blockIdx.x * C;
  for (int c = tid; c < C; c += 256) s_cur[c] = bp[c];
  __syncthreads();
  const int chunk = (B + NB - 1) / NB;
  const int r0 = blockIdx.x * chunk;
  const int r1 = min(B, r0 + chunk);
  for (int i = r0 + tid; i < r1; i += 256) {
    const int l = labels[i];
    const int pos = atomicAdd(&s_cur[l], 1);
    pr[pos] = make_int2(i, l);
  }
}

// ---------------------------------------------------------------------------
// K4: streaming segmented sum over class-sorted rows. 8192 waves, 32 rows
// each, processed in batches of 8 so 8 independent 1KB row loads are in
// flight per wave. pr entries are wave-uniform scalar loads (issued early).
// ---------------------------------------------------------------------------
__device__ __forceinline__ void flush_acc(float* __restrict__ sums, int c,
                                          const fx4& a, int lane) {
  float* dst = sums + (size_t)c * DIM + lane * 4;
  atomicAdd(dst + 0, a.x);
  atomicAdd(dst + 1, a.y);
  atomicAdd(dst + 2, a.z);
  atomicAdd(dst + 3, a.w);
}

__global__ __launch_bounds__(256) void k_segsum(const float* __restrict__ x,
                                                const int2* __restrict__ pr,
                                                float* __restrict__ sums,
                                                int B) {
  const int lane = threadIdx.x & 63;
  const int wid = __builtin_amdgcn_readfirstlane(
      (blockIdx.x << 2) | (threadIdx.x >> 6));
  const int nw = SSB * 4;
  const int per = (B + nw - 1) / nw;  // 32 for B=262144
  const int r0 = wid * per;
  const int r1 = min(B, r0 + per);
  if (r0 >= r1) return;

  fx4 acc = {0.f, 0.f, 0.f, 0.f};
  int prev = -1;
  int rb = r0;

  for (; rb + 8 <= r1; rb += 8) {
    int2 e[8];
#pragma unroll
    for (int k = 0; k < 8; ++k) e[k] = pr[rb + k];  // uniform -> s_load
    fx4 v[8];
#pragma unroll
    for (int k = 0; k < 8; ++k)  // 8 independent 1KB coalesced loads
      v[k] = __builtin_nontemporal_load(
          (const fx4*)(x + (size_t)e[k].x * DIM) + lane);
    float ss[8];
#pragma unroll
    for (int k = 0; k < 8; ++k)
      ss[k] = v[k].x * v[k].x + v[k].y * v[k].y + v[k].z * v[k].z +
              v[k].w * v[k].w;
#pragma unroll
    for (int off = 32; off; off >>= 1) {  // 8 interleaved reduce chains
#pragma unroll
      for (int k = 0; k < 8; ++k) ss[k] += __shfl_xor(ss[k], off);
    }
#pragma unroll
    for (int k = 0; k < 8; ++k) {
      const float inv = 1.f / fmaxf(sqrtf(ss[k]), 1e-12f);
      const int lab = e[k].y;
      if (lab != prev) {  // wave-uniform (scalar) branch
        if (prev >= 0) flush_acc(sums, prev, acc, lane);
        acc = (fx4){0.f, 0.f, 0.f, 0.f};
        prev = lab;
      }
      acc.x += v[k].x * inv; acc.y += v[k].y * inv;
      acc.z += v[k].z * inv; acc.w += v[k].w * inv;
    }
  }
  for (; rb < r1; ++rb) {  // tail (unused when B % (8*nw) == 0)
    const int2 e = pr[rb];
    const fx4 v = ((const fx4*)(x + (size_t)e.x * DIM))[lane];
    float ss = v.x * v.x + v.y * v.y + v.z * v.z + v.w * v.w;
#pragma unroll
    for (int off = 32; off; off >>= 1) ss += __shfl_xor(ss, off);
    const float inv = 1.f / fmaxf(sqrtf(ss), 1e-12f);
    if (e.y != prev) {
      if (prev >= 0) flush_acc(sums, prev, acc, lane);
      acc = (fx4){0.f, 0.f, 0.f, 0.f};
      prev = e.y;
    }
    acc.x += v.x * inv; acc.y += v.y * inv;
    acc.z += v.z * inv; acc.w += v.w * inv;
  }
  if (prev >= 0) flush_acc(sums, prev, acc, lane);
}

// ---------------------------------------------------------------------------
// K5: per-class norm, block-sum, one atomic per block into out[0]; then final.
// ---------------------------------------------------------------------------
__global__ __launch_bounds__(256) void k_norm(const float* __restrict__ sums,
                                              float* __restrict__ out, int C) {
  const int wave = threadIdx.x >> 6;
  const int lane = threadIdx.x & 63;
  const int c = blockIdx.x * 4 + wave;
  float term = 0.f;
  if (c < C) {
    const fx4 v = ((const fx4*)(sums + (size_t)c * DIM))[lane];
    float ss = v.x * v.x + v.y * v.y + v.z * v.z + v.w * v.w;
#pragma unroll
    for (int off = 32; off; off >>= 1) ss += __shfl_xor(ss, off);
    term = sqrtf(ss);  // 0 for empty classes, matching reference
  }
  __shared__ float sp[4];
  if (lane == 0) sp[wave] = term;
  __syncthreads();
  if (threadIdx.x == 0) atomicAdd(out, sp[0] + sp[1] + sp[2] + sp[3]);
}

__global__ void k_final(float* __restrict__ out, int B) {
  out[0] = 1.f - out[0] / (float)B;
}

extern "C" void kernel_launch(void* const* d_in, const int* in_sizes, int n_in,
                              void* d_out, int out_size, void* d_ws, size_t ws_size,
                              hipStream_t stream) {
  const float* x      = (const float*)d_in[0];
  const int*   labels = (const int*)d_in[1];
  const int B = in_sizes[1];
  const int C = 1000;  // fixed by problem setup

  // ws layout: hist[NB*C] ints | pr[B] int2 | sums[C*DIM] floats
  char* ws = (char*)d_ws;
  int*   hist = (int*)ws;
  size_t off = ((size_t)NB * C * sizeof(int) + 15) & ~(size_t)15;
  int2*  pr   = (int2*)(ws + off);
  off += (size_t)B * sizeof(int2);
  float* sums = (float*)(ws + off);

  const size_t lds_c = (size_t)C * sizeof(int);
  k_hist<<<NB, 256, lds_c, stream>>>(labels, hist, sums, B, C);
  k_scan<<<1, 1024, 0, stream>>>(hist, (float*)d_out, C);
  k_permute<<<NB, 256, lds_c, stream>>>(labels, hist, pr, B, C);
  k_segsum<<<SSB, 256, 0, stream>>>(x, pr, sums, B);
  k_norm<<<(C + 3) / 4, 256, 0, stream>>>(sums, (float*)d_out, C);
  k_final<<<1, 1, 0, stream>>>((float*)d_out, B);
}